// Round 5
// baseline (77.181 us; speedup 1.0000x reference)
//
#include <hip/hip_runtime.h>

// MultiPositiveContrastiveLoss: B=32768 problems, C=64 candidates, P=16 pos, N=48 neg.
// v6: two-kernel skeleton (best measured). Partial kernel now processes 8 problems/wave
// (halves wave count 8192->4096, doubles batched MLP: 16 score + 8 idx + 4 count-quad
// loads in flight per wave, halves per-wave reduce/drain overhead).
// BIT-EXACTNESS: the 2048-slot partials array is preserved bit-identically to v5 by
// keeping TWO accumulator pairs per wave (k=0-3 -> A, k=4-7 -> B), butterfly-reducing
// each separately (same op sequence as the two old waves they replace), and combining
// via LDS in the exact old wave order (lds[0..3] -> slot 2*blk, lds[4..7] -> 2*blk+1).
// Final kernel unchanged -> absmax stays 0.0.

#define MARGIN 0.5f

constexpr int C = 64;
constexpr int P = 16;
constexpr int N = 48;
constexpr int BLOCK = 256;
constexpr int WAVES_PER_BLOCK = BLOCK / 64;              // 4
constexpr int PROBS_PER_WAVE = 8;                        // 2 "old waves" worth
constexpr int PROBS_PER_BLOCK = WAVES_PER_BLOCK * PROBS_PER_WAVE;   // 32
constexpr int SLOTS_PER_BLOCK = 2;                       // old 16-problem partial slots
constexpr int PROBS_PER_SLOT = 16;

__device__ __forceinline__ float readlane_f(float v, int l) {
    return __uint_as_float(__builtin_amdgcn_readlane(__float_as_uint(v), l));
}

__global__ __launch_bounds__(BLOCK) void mpcl_partial_kernel(
    const float* __restrict__ scores,
    const int*   __restrict__ pos_indices,
    const int*   __restrict__ neg_indices,
    const int*   __restrict__ pos_counts,
    const int*   __restrict__ neg_counts,
    float2*      __restrict__ partials,
    int B)
{
    const int lane = threadIdx.x & 63;
    const int wave = threadIdx.x >> 6;
    const int b0 = (blockIdx.x * WAVES_PER_BLOCK + wave) * PROBS_PER_WAVE;

    float totA = 0.0f, cntA = 0.0f;   // problems k=0..3  (old even wave)
    float totB = 0.0f, cntB = 0.0f;   // problems k=4..7  (old odd wave)

    if (b0 + PROBS_PER_WAVE <= B) {
        // ---- fast path: batch ALL loads, zero dependency levels between them ----
        // counts: b0 % 8 == 0 -> aligned wave-uniform dwordx4 pairs
        const int4 pcL = *reinterpret_cast<const int4*>(pos_counts + b0);
        const int4 pcH = *reinterpret_cast<const int4*>(pos_counts + b0 + 4);
        const int4 ncL = *reinterpret_cast<const int4*>(neg_counts + b0);
        const int4 ncH = *reinterpret_cast<const int4*>(neg_counts + b0 + 4);
        const int pc[PROBS_PER_WAVE] = { pcL.x, pcL.y, pcL.z, pcL.w,
                                         pcH.x, pcH.y, pcH.z, pcH.w };
        const int nc[PROBS_PER_WAVE] = { ncL.x, ncL.y, ncL.z, ncL.w,
                                         ncH.x, ncH.y, ncH.z, ncH.w };

        int   idx[PROBS_PER_WAVE];
        float sc[PROBS_PER_WAVE];
        #pragma unroll
        for (int k = 0; k < PROBS_PER_WAVE; ++k) {
            const int b = b0 + k;
            // one load instruction per problem: per-lane pointer select
            const int* ip = (lane >= 48)
                ? pos_indices + (size_t)b * P + (lane - 48)
                : neg_indices + (size_t)b * N + lane;
            idx[k] = *ip;                                // idx in [0,C)
            sc[k]  = scores[(size_t)b * C + lane];       // fully coalesced: C == 64
        }

        #pragma unroll
        for (int k = 0; k < PROBS_PER_WAVE; ++k) {
            const float val  = __shfl(sc[k], idx[k]);    // in-wave gather (ds_bpermute)
            // lanes >= 48 act as permanently-invalid negs (nc <= 48)
            const float negv = (lane < nc[k]) ? val : -1e30f;
            // invalid pos -> +1e30 -> (mneg - pos_i) <= -1e29 -> relu term exactly 0.0f
            const float posv = (lane >= 48 && (lane - 48) < pc[k]) ? val : 1e30f;
            const float mneg = MARGIN + negv;

            float s = 0.0f;
            #pragma unroll
            for (int i = 0; i < P; ++i) {
                s += fmaxf(mneg - readlane_f(posv, 48 + i), 0.0f);
            }
            if (k < 4) { totA += s; cntA += (float)(pc[k] * nc[k]); }
            else       { totB += s; cntB += (float)(pc[k] * nc[k]); }
        }
    } else {
        // ---- tail path (never taken for B=32768, kept for generality) ----
        for (int k = 0; k < PROBS_PER_WAVE; ++k) {
            const int b = b0 + k;
            if (b >= B) break;
            const int pcs = pos_counts[b];
            const int ncs = neg_counts[b];
            float myval  = 0.0f;
            float negval = -1e30f;
            if (lane >= 48) {
                const int ix = pos_indices[(size_t)b * P + (lane - 48)];
                myval = scores[(size_t)b * C + ix];
            } else if (lane < ncs) {
                const int ix = neg_indices[(size_t)b * N + lane];
                negval = scores[(size_t)b * C + ix];
            }
            float s = 0.0f;
            for (int i = 0; i < pcs; ++i) {
                const float pos_i = __shfl(myval, 48 + i);
                s += fmaxf(MARGIN - pos_i + negval, 0.0f);
            }
            if (k < 4) { totA += s; cntA += (float)(pcs * ncs); }
            else       { totB += s; cntB += (float)(pcs * ncs); }
        }
    }

    // butterfly-reduce each half separately — identical op sequence to the two old waves
    #pragma unroll
    for (int off = 32; off; off >>= 1) {
        totA += __shfl_xor(totA, off);
        totB += __shfl_xor(totB, off);
    }

    // lds slots in OLD wave order: new wave w -> old waves 2w (A) and 2w+1 (B)
    __shared__ float2 lds[2 * WAVES_PER_BLOCK];
    if (lane == 0) {
        lds[2 * wave + 0] = make_float2(totA, cntA);
        lds[2 * wave + 1] = make_float2(totB, cntB);
    }
    __syncthreads();

    if (threadIdx.x == 0) {
        // slot 0: old block 2*blk  (lds[0..3]);  slot 1: old block 2*blk+1 (lds[4..7])
        #pragma unroll
        for (int s = 0; s < SLOTS_PER_BLOCK; ++s) {
            float2 acc = lds[4 * s];
            #pragma unroll
            for (int w = 1; w < 4; ++w) {
                acc.x += lds[4 * s + w].x;
                acc.y += lds[4 * s + w].y;
            }
            partials[SLOTS_PER_BLOCK * blockIdx.x + s] = acc;
        }
    }
}

__global__ __launch_bounds__(BLOCK) void mpcl_final_kernel(
    const float2* __restrict__ partials, int n, float* __restrict__ out)
{
    float tot = 0.0f, cnt = 0.0f;
    for (int i = threadIdx.x; i < n; i += BLOCK) {
        const float2 p = partials[i];
        tot += p.x;
        cnt += p.y;
    }
    #pragma unroll
    for (int off = 32; off; off >>= 1) {
        tot += __shfl_xor(tot, off);
        cnt += __shfl_xor(cnt, off);
    }

    __shared__ float2 lds[WAVES_PER_BLOCK];
    const int wave = threadIdx.x >> 6;
    const int lane = threadIdx.x & 63;
    if (lane == 0) lds[wave] = make_float2(tot, cnt);
    __syncthreads();

    if (threadIdx.x == 0) {
        float T = 0.0f, Cn = 0.0f;
        #pragma unroll
        for (int w = 0; w < WAVES_PER_BLOCK; ++w) { T += lds[w].x; Cn += lds[w].y; }
        out[0] = (Cn > 0.0f) ? (T / fmaxf(Cn, 1.0f)) : 0.0f;
    }
}

extern "C" void kernel_launch(void* const* d_in, const int* in_sizes, int n_in,
                              void* d_out, int out_size, void* d_ws, size_t ws_size,
                              hipStream_t stream) {
    const float* scores      = (const float*)d_in[0];
    const int*   pos_indices = (const int*)d_in[1];
    const int*   neg_indices = (const int*)d_in[2];
    const int*   pos_counts  = (const int*)d_in[3];
    const int*   neg_counts  = (const int*)d_in[4];
    float*       out         = (float*)d_out;

    const int B = in_sizes[3];                                    // 32768
    const int grid   = (B + PROBS_PER_BLOCK - 1) / PROBS_PER_BLOCK;   // 1024
    const int nslots = (B + PROBS_PER_SLOT - 1) / PROBS_PER_SLOT;     // 2048 (same as v5)

    float2* partials = (float2*)d_ws;                // 2048 * 8 B = 16 KB

    mpcl_partial_kernel<<<grid, BLOCK, 0, stream>>>(
        scores, pos_indices, neg_indices, pos_counts, neg_counts, partials, B);
    mpcl_final_kernel<<<1, BLOCK, 0, stream>>>(partials, nslots, out);
}

// Round 6
// 76.570 us; speedup vs baseline: 1.0080x; 1.0080x over previous
//
#include <hip/hip_runtime.h>

// MultiPositiveContrastiveLoss: B=32768 problems, C=64 candidates, P=16 pos, N=48 neg.
// v7 == v5 (terminal revert; best measured at 75.6 us).
// Session findings baked into this structure:
//   - Two-kernel skeleton beats fusion: the kernel boundary is the cheapest grid-wide
//     barrier (v3 acq-rel ticket = +50 us contention; v4 2-level ticket still net loss).
//   - 4 problems/wave beats 8 (v6 +1.6 us): 8192 waves of short work hide the serial
//     readlane chain better than 4096 waves of doubled work.
//   - All loads batched dependency-free; scores lane-coalesced (C==64) with candidate
//     indirection resolved in-wave via ds_bpermute; idx via per-lane pointer select;
//     counts via wave-uniform s_load_dwordx4.
//   - Fixed 16-trip readlane inner loop; invalid pos masked with +1e30 (term == 0.0f,
//     valid-term accumulation order preserved -> absmax 0.0).
// Remaining time is harness-fixed: 42 us workspace poison-fill + ~23 us reset dispatches;
// controllable slice ~10 us vs ~6 us floor (HBM re-fetch after L3 sweep + 2 nodes).

#define MARGIN 0.5f

constexpr int C = 64;
constexpr int P = 16;
constexpr int N = 48;
constexpr int BLOCK = 256;
constexpr int WAVES_PER_BLOCK = BLOCK / 64;      // 4
constexpr int PROBS_PER_WAVE = 4;
constexpr int PROBS_PER_BLOCK = WAVES_PER_BLOCK * PROBS_PER_WAVE;  // 16

__device__ __forceinline__ float readlane_f(float v, int l) {
    return __uint_as_float(__builtin_amdgcn_readlane(__float_as_uint(v), l));
}

__global__ __launch_bounds__(BLOCK) void mpcl_partial_kernel(
    const float* __restrict__ scores,
    const int*   __restrict__ pos_indices,
    const int*   __restrict__ neg_indices,
    const int*   __restrict__ pos_counts,
    const int*   __restrict__ neg_counts,
    float2*      __restrict__ partials,
    int B)
{
    const int lane = threadIdx.x & 63;
    const int wave = threadIdx.x >> 6;
    const int b0 = (blockIdx.x * WAVES_PER_BLOCK + wave) * PROBS_PER_WAVE;

    float tot = 0.0f;
    float cnt = 0.0f;

    if (b0 + PROBS_PER_WAVE <= B) {
        // ---- fast path: batch ALL loads, zero dependency levels between them ----
        // counts: b0 % 4 == 0 -> 16B-aligned, wave-uniform -> s_load_dwordx4
        const int4 pc4 = *reinterpret_cast<const int4*>(pos_counts + b0);
        const int4 nc4 = *reinterpret_cast<const int4*>(neg_counts + b0);
        const int pc[PROBS_PER_WAVE] = { pc4.x, pc4.y, pc4.z, pc4.w };
        const int nc[PROBS_PER_WAVE] = { nc4.x, nc4.y, nc4.z, nc4.w };

        int   idx[PROBS_PER_WAVE];
        float sc[PROBS_PER_WAVE];
        #pragma unroll
        for (int k = 0; k < PROBS_PER_WAVE; ++k) {
            const int b = b0 + k;
            // one load instruction per problem: per-lane pointer select
            const int* ip = (lane >= 48)
                ? pos_indices + (size_t)b * P + (lane - 48)
                : neg_indices + (size_t)b * N + lane;
            idx[k] = *ip;                                // idx in [0,C)
            sc[k]  = scores[(size_t)b * C + lane];       // fully coalesced: C == 64
        }

        #pragma unroll
        for (int k = 0; k < PROBS_PER_WAVE; ++k) {
            const float val  = __shfl(sc[k], idx[k]);    // in-wave gather (ds_bpermute)
            // lanes >= 48 act as permanently-invalid negs (nc <= 48)
            const float negv = (lane < nc[k]) ? val : -1e30f;
            // invalid pos -> +1e30 -> (mneg - pos_i) <= -1e29 -> relu term exactly 0.0f
            const float posv = (lane >= 48 && (lane - 48) < pc[k]) ? val : 1e30f;
            const float mneg = MARGIN + negv;

            float s = 0.0f;
            #pragma unroll
            for (int i = 0; i < P; ++i) {
                s += fmaxf(mneg - readlane_f(posv, 48 + i), 0.0f);
            }
            tot += s;
            cnt += (float)(pc[k] * nc[k]);               // closed-form pair count
        }
    } else {
        // ---- tail path (never taken for B=32768, kept for generality) ----
        for (int k = 0; k < PROBS_PER_WAVE; ++k) {
            const int b = b0 + k;
            if (b >= B) break;
            const int pc = pos_counts[b];
            const int nc = neg_counts[b];
            float myval  = 0.0f;
            float negval = -1e30f;
            if (lane >= 48) {
                const int idx = pos_indices[(size_t)b * P + (lane - 48)];
                myval = scores[(size_t)b * C + idx];
            } else if (lane < nc) {
                const int idx = neg_indices[(size_t)b * N + lane];
                negval = scores[(size_t)b * C + idx];
            }
            float s = 0.0f;
            for (int i = 0; i < pc; ++i) {
                const float pos_i = __shfl(myval, 48 + i);
                s += fmaxf(MARGIN - pos_i + negval, 0.0f);
            }
            tot += s;
            cnt += (float)(pc * nc);
        }
    }

    // wave reduce total (count is wave-uniform already)
    #pragma unroll
    for (int off = 32; off; off >>= 1) tot += __shfl_xor(tot, off);

    __shared__ float2 lds[WAVES_PER_BLOCK];
    if (lane == 0) lds[wave] = make_float2(tot, cnt);
    __syncthreads();

    if (threadIdx.x == 0) {
        float2 acc = lds[0];
        #pragma unroll
        for (int w = 1; w < WAVES_PER_BLOCK; ++w) { acc.x += lds[w].x; acc.y += lds[w].y; }
        partials[blockIdx.x] = acc;     // plain store; kernel boundary = visibility fence
    }
}

__global__ __launch_bounds__(BLOCK) void mpcl_final_kernel(
    const float2* __restrict__ partials, int n, float* __restrict__ out)
{
    float tot = 0.0f, cnt = 0.0f;
    for (int i = threadIdx.x; i < n; i += BLOCK) {
        const float2 p = partials[i];
        tot += p.x;
        cnt += p.y;
    }
    #pragma unroll
    for (int off = 32; off; off >>= 1) {
        tot += __shfl_xor(tot, off);
        cnt += __shfl_xor(cnt, off);
    }

    __shared__ float2 lds[WAVES_PER_BLOCK];
    const int wave = threadIdx.x >> 6;
    const int lane = threadIdx.x & 63;
    if (lane == 0) lds[wave] = make_float2(tot, cnt);
    __syncthreads();

    if (threadIdx.x == 0) {
        float T = 0.0f, Cn = 0.0f;
        #pragma unroll
        for (int w = 0; w < WAVES_PER_BLOCK; ++w) { T += lds[w].x; Cn += lds[w].y; }
        out[0] = (Cn > 0.0f) ? (T / fmaxf(Cn, 1.0f)) : 0.0f;
    }
}

extern "C" void kernel_launch(void* const* d_in, const int* in_sizes, int n_in,
                              void* d_out, int out_size, void* d_ws, size_t ws_size,
                              hipStream_t stream) {
    const float* scores      = (const float*)d_in[0];
    const int*   pos_indices = (const int*)d_in[1];
    const int*   neg_indices = (const int*)d_in[2];
    const int*   pos_counts  = (const int*)d_in[3];
    const int*   neg_counts  = (const int*)d_in[4];
    float*       out         = (float*)d_out;

    const int B = in_sizes[3];                       // 32768
    const int grid = (B + PROBS_PER_BLOCK - 1) / PROBS_PER_BLOCK;  // 2048

    float2* partials = (float2*)d_ws;                // 2048 * 8 B = 16 KB

    mpcl_partial_kernel<<<grid, BLOCK, 0, stream>>>(
        scores, pos_indices, neg_indices, pos_counts, neg_counts, partials, B);
    mpcl_final_kernel<<<1, BLOCK, 0, stream>>>(partials, grid, out);
}